// Round 9
// baseline (107.552 us; speedup 1.0000x reference)
//
#include <hip/hip_runtime.h>

#define BB 8
#define NN 2048
#define FF 128
#define MT 128

typedef short bh8 __attribute__((ext_vector_type(8)));
typedef float fl4 __attribute__((ext_vector_type(4)));
typedef unsigned short u16;
typedef unsigned long long u64;

__device__ __forceinline__ u16 f2bf(float x) {
    unsigned u = __float_as_uint(x);
    return (u16)((u + 0x7FFFu + ((u >> 16) & 1u)) >> 16);
}

// ---------------------------------------------------------------------------
// kernel 1: ballot-free adjacency bit-pack. Thread t packs ints [64t,64t+64)
// via 16 independent int4 loads -> nibble trick -> one coalesced u64 store.
// ---------------------------------------------------------------------------
__global__ __launch_bounds__(256) void k_pack(
    const int* __restrict__ adj, u64* __restrict__ bm)
{
    const long gt = (long)blockIdx.x * 256 + threadIdx.x;   // u64 index
    const int4* src = (const int4*)adj + gt * 16;
    u64 m = 0;
    #pragma unroll
    for (int i = 0; i < 16; ++i) {
        const int4 v = src[i];
        const unsigned nib = (v.x > 0 ? 1u : 0u) | (v.y > 0 ? 2u : 0u)
                           | (v.z > 0 ? 4u : 0u) | (v.w > 0 ? 8u : 0u);
        m |= (u64)nib << (4 * i);
    }
    bm[gt] = m;
}

// ---------------------------------------------------------------------------
// kernel 2: h = feat @ W + b -> htg bf16 transposed [b][o][n]; side outputs
// esrc, edst, eed = exp(edst), eed2 = exp(0.01*edst).
// ---------------------------------------------------------------------------
__global__ __launch_bounds__(256) void k_h(
    const float* __restrict__ feat, const float* __restrict__ W,
    const float* __restrict__ bias, const float* __restrict__ a,
    u16* __restrict__ htg, float* __restrict__ esrc, float* __restrict__ edst,
    float* __restrict__ eed, float* __restrict__ eed2)
{
    __shared__ float fsh[8][FF];
    __shared__ float red[2][2][8];
    const int t = threadIdx.x;
    const long row0 = (long)blockIdx.x * 8;

    ((float4*)&fsh[0][0])[t] = ((const float4*)(feat + row0 * FF))[t];
    __syncthreads();

    const int o = t & 127;
    const int half = t >> 7;
    float acc[4] = {0.f, 0.f, 0.f, 0.f};
    #pragma unroll 4
    for (int k = 0; k < FF; ++k) {
        const float w = W[k * FF + o];
        #pragma unroll
        for (int r = 0; r < 4; ++r)
            acc[r] = fmaf(fsh[half * 4 + r][k], w, acc[r]);
    }
    const float bo = bias[o];
    const float as = a[o];
    const float ad = a[FF + o];
    float ps[4], pd[4];
    #pragma unroll
    for (int r = 0; r < 4; ++r) {
        acc[r] += bo;
        ps[r] = acc[r] * as;
        pd[r] = acc[r] * ad;
    }
    {
        const int bI = (int)(row0 >> 11);
        const int nloc = (int)(row0 & 2047) + half * 4;
        ushort4 hv;
        hv.x = f2bf(acc[0]); hv.y = f2bf(acc[1]);
        hv.z = f2bf(acc[2]); hv.w = f2bf(acc[3]);
        *(ushort4*)&htg[((long)bI * FF + o) * NN + nloc] = hv;
    }
    #pragma unroll
    for (int r = 0; r < 4; ++r) {
        #pragma unroll
        for (int off = 32; off > 0; off >>= 1) {
            ps[r] += __shfl_down(ps[r], off, 64);
            pd[r] += __shfl_down(pd[r], off, 64);
        }
    }
    const int wv = (t >> 6) & 1;
    if ((t & 63) == 0) {
        #pragma unroll
        for (int r = 0; r < 4; ++r) {
            red[half][wv][r]     = ps[r];
            red[half][wv][4 + r] = pd[r];
        }
    }
    __syncthreads();
    if (t < 16) {
        const int hh = t >> 3, idx = t & 7;
        const float v = red[hh][0][idx] + red[hh][1][idx];
        const long row = row0 + hh * 4 + (idx & 3);
        if (idx < 4) {
            esrc[row] = v;
        } else {
            edst[row] = v;
            eed[row]  = __expf(v);
            eed2[row] = __expf(0.01f * v);
        }
    }
}

// ---------------------------------------------------------------------------
// kernel 3: 64-row blocks, 4 waves ROW-split (wave w = rows w*16..w*16+15).
// Per 128-m window: H-tile (128x128 bf16, 32KB) staged global->reg->LDS,
// double-buffered, XOR-swizzled (chunk ^= row&7) -> conflict-free b128 on
// both sides. One __syncthreads per window. A-frags built in registers from
// bitmask + exp tables: exp(leaky(es+ed)-M) = max(A*E, Bv*F), masked.
// No cross-wave reduce (each wave owns its rows end-to-end).
// ---------------------------------------------------------------------------
__global__ __launch_bounds__(256, 1) void k_attn(
    const u64* __restrict__ bm, const float* __restrict__ mask,
    const u16* __restrict__ htg, const float* __restrict__ esrc,
    const float* __restrict__ edst, const float* __restrict__ eed,
    const float* __restrict__ eed2, float* __restrict__ out)
{
    __shared__ u16 Hs[2][128][128];   // 64 KB, double-buffered H window

    const int t = threadIdx.x;
    const int b = blockIdx.x & 7;               // batch -> XCD affinity
    const int n0 = (blockIdx.x >> 3) * 64;      // 32 row-blocks per batch
    const int w = t >> 6, lane = t & 63;
    const int lr = lane & 15, g = lane >> 4;

    // per-wave gmax over edst[b][:] (8 KB, L2-hot)
    float gmx = -3.4e38f;
    {
        const float4* edp = (const float4*)(edst + b * NN);
        #pragma unroll
        for (int i = 0; i < 8; ++i) {
            const float4 v = edp[lane + 64 * i];
            gmx = fmaxf(gmx, fmaxf(fmaxf(v.x, v.y), fmaxf(v.z, v.w)));
        }
        #pragma unroll
        for (int off = 32; off > 0; off >>= 1)
            gmx = fmaxf(gmx, __shfl_xor(gmx, off, 64));
    }

    const int myrow = n0 + w * 16 + lr;          // this lane's P row
    const float es = esrc[b * NN + myrow];
    const float mt = es + gmx;
    const float M = fmaxf(mt, 0.01f * mt);       // leaky(es+gmax) >= rowmax
    const float A  = __expf(es - M);
    const float Bv = __expf(0.01f * es - M);

    const uint4*  bmb  = (const uint4*)(bm + (long)b * NN * 32);   // [row][16]
    const float4* eebw = (const float4*)(eed + b * NN);
    const float4* ee2w = (const float4*)(eed2 + b * NN);
    const u16*    htgB = htg + (long)b * FF * NN;

    // staging geometry: thread t, issue i covers LDS linear bytes
    // [i*4096 + t*16, +16); row = i*16 + (t>>4); lds chunk = t&15;
    // swizzle: lds[row][c] = global[row][c ^ (row&7)]
    const int srow   = t >> 4;                        // 0..15 (+16*i)
    const int schunk = (t & 15) ^ (srow & 7);
    const u16* sbase = htgB + srow * NN + schunk * 8; // + i*16*NN + win*128

    fl4 acc[8];
    #pragma unroll
    for (int ct = 0; ct < 8; ++ct) acc[ct] = (fl4){0.f, 0.f, 0.f, 0.f};
    float psum = 0.f;

    // prologue: stage window 0 into buffer 0
    {
        float4 hr[8];
        #pragma unroll
        for (int i = 0; i < 8; ++i)
            hr[i] = *(const float4*)(sbase + (long)i * 16 * NN);
        u16* hd = &Hs[0][0][0];
        #pragma unroll
        for (int i = 0; i < 8; ++i)
            *(float4*)(hd + i * 2048 + t * 8) = hr[i];
    }
    uint4 bqA = bmb[myrow * 16];
    __syncthreads();

    int cur = 0;
    #pragma unroll 1
    for (int win = 0; win < 16; ++win) {
        const int wn = (win + 1) & 15;

        // 1) early-issue next window's H chunk into registers
        float4 hr[8];
        #pragma unroll
        for (int i = 0; i < 8; ++i)
            hr[i] = *(const float4*)(sbase + (long)i * 16 * NN + wn * MT);

        // 2) next window's bitmask
        const uint4 bqB = bmb[myrow * 16 + wn];

        // 3) A-fragments in registers: P = bit ? max(A*E, Bv*F) : 0
        bh8 af[4];
        #pragma unroll
        for (int kc = 0; kc < 4; ++kc) {
            const unsigned q = (kc == 0) ? bqA.x : (kc == 1) ? bqA.y
                             : (kc == 2) ? bqA.z : bqA.w;
            const unsigned by = (q >> (8 * g)) & 0xFFu;
            const float4 Ea = eebw[win * 32 + kc * 8 + g * 2];
            const float4 Eb = eebw[win * 32 + kc * 8 + g * 2 + 1];
            const float4 Fa = ee2w[win * 32 + kc * 8 + g * 2];
            const float4 Fb = ee2w[win * 32 + kc * 8 + g * 2 + 1];
            const float pe[8] = {Ea.x, Ea.y, Ea.z, Ea.w, Eb.x, Eb.y, Eb.z, Eb.w};
            const float pf[8] = {Fa.x, Fa.y, Fa.z, Fa.w, Fb.x, Fb.y, Fb.z, Fb.w};
            #pragma unroll
            for (int j = 0; j < 8; ++j) {
                const float v = ((by >> j) & 1u)
                              ? fmaxf(A * pe[j], Bv * pf[j]) : 0.f;
                const u16 ub = f2bf(v);
                af[kc][j] = (short)ub;
                // psum accumulates ROUNDED values (num/denom consistent)
                psum += __uint_as_float((unsigned)ub << 16);
            }
        }

        // 4) MFMA phase: B-frags from swizzled LDS (row&7 == lr&7)
        #pragma unroll
        for (int kc = 0; kc < 4; ++kc) {
            const int ch = ((kc << 2) + g) ^ (lr & 7);
            #pragma unroll
            for (int ct = 0; ct < 8; ++ct) {
                const bh8 bf = *(const bh8*)&Hs[cur][ct * 16 + lr][ch * 8];
                acc[ct] = __builtin_amdgcn_mfma_f32_16x16x32_bf16(af[kc], bf, acc[ct], 0, 0, 0);
            }
        }

        // 5) stage next window into the other buffer (safe: that buffer's
        // readers finished before the previous barrier)
        {
            u16* hd = &Hs[cur ^ 1][0][0];
            #pragma unroll
            for (int i = 0; i < 8; ++i)
                *(float4*)(hd + i * 2048 + t * 8) = hr[i];
        }
        // 6) publish
        __syncthreads();
        bqA = bqB;
        cur ^= 1;
    }

    // psum reduce across g-groups (lanes lr, lr+16, lr+32, lr+48)
    psum += __shfl_xor(psum, 16, 64);
    psum += __shfl_xor(psum, 32, 64);

    // epilogue: C/D layout col=ct*16+lr, row=g*4+reg [m89/m91]; wave-local rows
    const long obase = ((long)b * NN + n0 + w * 16) * FF;
    #pragma unroll
    for (int reg = 0; reg < 4; ++reg) {
        const int r = g * 4 + reg;
        const float pr = __shfl(psum, r, 64);   // lane r (g=0, lr=r) holds row r
        const float sc = mask[b * NN + n0 + w * 16 + r] / pr;
        #pragma unroll
        for (int ct = 0; ct < 8; ++ct)
            out[obase + (long)r * FF + ct * 16 + lr] = acc[ct][reg] * sc;
    }
}

// ---------------------------------------------------------------------------
extern "C" void kernel_launch(void* const* d_in, const int* in_sizes, int n_in,
                              void* d_out, int out_size, void* d_ws, size_t ws_size,
                              hipStream_t stream)
{
    const float* feat = (const float*)d_in[0];
    const int*   adj  = (const int*)d_in[1];
    const float* mask = (const float*)d_in[2];
    const float* W    = (const float*)d_in[3];
    const float* bias = (const float*)d_in[4];
    const float* a    = (const float*)d_in[5];
    float* out = (float*)d_out;

    // ws: htg bf16 [8][128][2048] | esrc | edst | eed | eed2 (f32 64KB each) | bm 4MB
    u16*   htg  = (u16*)d_ws;
    float* esrc = (float*)(htg + (size_t)BB * FF * NN);
    float* edst = esrc + BB * NN;
    float* eed  = edst + BB * NN;
    float* eed2 = eed + BB * NN;
    u64*   bmp  = (u64*)(eed2 + BB * NN);

    k_pack<<<BB * NN * NN / 64 / 256, 256, 0, stream>>>(adj, bmp);
    k_h   <<<BB * NN / 8, 256, 0, stream>>>(feat, W, bias, a, htg, esrc, edst, eed, eed2);
    k_attn<<<BB * (NN / 64), 256, 0, stream>>>(bmp, mask, htg, esrc, edst, eed, eed2, out);
}